// Round 2
// baseline (91.849 us; speedup 1.0000x reference)
//
#include <hip/hip_runtime.h>

// QuantumLSTMCell fused single-kernel version.
// Per row: u = W*x+b; joint = outer(u,h)/(|u||h|); psi = C*joint; p = psi^2;
// h_next[a] = sum_s p[4s+a]; out = sum_r z_r p_r.
// Folded: psi_r * |u||h| = x*(A_r.h) + (Bm_r.h), with A/Bm 16x4 built per-block
// in LDS from the 16 angles (cost ~1us total, removes 2nd kernel + global AB).
// Each lane processes 4 rows so every LDS constant broadcast is amortized 4x.

__device__ __forceinline__ int ring_perm(int k) {
  // CNOT(0,1), CNOT(1,2), CNOT(2,3), CNOT(3,0) in sequence; wire 0 = MSB.
  int b0 = (k >> 3) & 1, b1 = (k >> 2) & 1, b2 = (k >> 1) & 1, b3 = k & 1;
  b1 ^= b0; b2 ^= b1; b3 ^= b2; b0 ^= b3;
  return (b0 << 3) | (b1 << 2) | (b2 << 1) | b3;
}

__global__ __launch_bounds__(256) void qlstm_fused_kernel(
    const float* __restrict__ x, const float4* __restrict__ h_prev,
    const float* __restrict__ W_in, const float* __restrict__ b_in,
    const float* __restrict__ U, const float* __restrict__ Ud,
    float4* __restrict__ h_next, float* __restrict__ outp, int B) {
  __shared__ float M[16][16];   // running circuit product
  __shared__ float Lm[16][16];  // current layer unitary
  __shared__ float AB[132];     // A[64], Bm[64], qa, qb, qc

  const int t = threadIdx.x;
  {
    const int i = t >> 4, j = t & 15;
    const int pi = ring_perm(i);

    // weights order: U[0], U[1], Udagger[1], Udagger[0]
    float ang[4][4];
#pragma unroll
    for (int q = 0; q < 4; ++q) {
      ang[0][q] = U[q];
      ang[1][q] = U[4 + q];
      ang[2][q] = Ud[4 + q];
      ang[3][q] = Ud[q];
    }

    // layer 0: M = RING @ kron(RY(w0)..RY(w3))  (scatter through perm)
    {
      float kel = 1.f;
#pragma unroll
      for (int q = 0; q < 4; ++q) {
        float c = cosf(0.5f * ang[0][q]);
        float s = sinf(0.5f * ang[0][q]);
        int iq = (i >> (3 - q)) & 1, jq = (j >> (3 - q)) & 1;
        kel *= (iq == jq) ? c : (iq ? s : -s);
      }
      M[pi][j] = kel;
    }
    __syncthreads();

    for (int l = 1; l < 4; ++l) {
      float kel = 1.f;
#pragma unroll
      for (int q = 0; q < 4; ++q) {
        float c = cosf(0.5f * ang[l][q]);
        float s = sinf(0.5f * ang[l][q]);
        int iq = (i >> (3 - q)) & 1, jq = (j >> (3 - q)) & 1;
        kel *= (iq == jq) ? c : (iq ? s : -s);
      }
      Lm[pi][j] = kel;
      __syncthreads();
      float acc = 0.f;
#pragma unroll
      for (int k = 0; k < 16; ++k) acc += Lm[i][k] * M[k][j];
      __syncthreads();  // all reads of M done before overwrite
      M[i][j] = acc;
      __syncthreads();
    }

    // A[r][k] = sum_i W_i * C[r][4i+k]; Bm likewise with b_i
    if (t < 64) {
      const int r = t >> 2, k = t & 3;
      float a = 0.f, bb = 0.f;
#pragma unroll
      for (int q = 0; q < 4; ++q) {
        float c = M[r][4 * q + k];
        a = fmaf(W_in[q], c, a);
        bb = fmaf(b_in[q], c, bb);
      }
      AB[r * 4 + k] = a;
      AB[64 + r * 4 + k] = bb;
    }
    if (t == 0) {
      float qa = 0.f, qb = 0.f, qc = 0.f;
#pragma unroll
      for (int q = 0; q < 4; ++q) {
        qa = fmaf(W_in[q], W_in[q], qa);
        qb = fmaf(2.f * W_in[q], b_in[q], qb);
        qc = fmaf(b_in[q], b_in[q], qc);
      }
      AB[128] = qa; AB[129] = qb; AB[130] = qc;
    }
    __syncthreads();
  }

  // ---- phase 2: 4 rows per lane ----
  const int gid = blockIdx.x * 256 + t;
  const int row0 = gid * 4;
  if (row0 >= B) return;

  const float qa = AB[128], qb = AB[129], qc = AB[130];

  if (row0 + 3 < B) {
    float4 xv4 = ((const float4*)x)[gid];
    float xv[4] = {xv4.x, xv4.y, xv4.z, xv4.w};
    float4 h[4];
#pragma unroll
    for (int m = 0; m < 4; ++m) h[m] = h_prev[row0 + m];

    float inv2[4];
#pragma unroll
    for (int m = 0; m < 4; ++m) {
      float nh2 = fmaf(h[m].x, h[m].x,
                  fmaf(h[m].y, h[m].y,
                  fmaf(h[m].z, h[m].z, h[m].w * h[m].w)));
      float nu2 = fmaf(fmaf(qa, xv[m], qb), xv[m], qc);
      inv2[m] = __builtin_amdgcn_rcpf(nu2 * nh2);
    }

    float hn[4][4] = {};
    float po[4] = {0.f, 0.f, 0.f, 0.f};
#pragma unroll
    for (int r = 0; r < 16; ++r) {
      const float a0 = AB[r * 4 + 0], a1 = AB[r * 4 + 1];
      const float a2 = AB[r * 4 + 2], a3 = AB[r * 4 + 3];
      const float b0 = AB[64 + r * 4 + 0], b1 = AB[64 + r * 4 + 1];
      const float b2 = AB[64 + r * 4 + 2], b3 = AB[64 + r * 4 + 3];
#pragma unroll
      for (int m = 0; m < 4; ++m) {
        float ar = fmaf(a0, h[m].x, fmaf(a1, h[m].y, fmaf(a2, h[m].z, a3 * h[m].w)));
        float br = fmaf(b0, h[m].x, fmaf(b1, h[m].y, fmaf(b2, h[m].z, b3 * h[m].w)));
        float tr = fmaf(xv[m], ar, br);
        float s = tr * tr;
        hn[m][r & 3] += s;
        po[m] += ((r >> 2) & 1) ? -s : s;
      }
    }

#pragma unroll
    for (int m = 0; m < 4; ++m) {
      float4 o;
      o.x = hn[m][0] * inv2[m];
      o.y = hn[m][1] * inv2[m];
      o.z = hn[m][2] * inv2[m];
      o.w = hn[m][3] * inv2[m];
      h_next[row0 + m] = o;
    }
    float4 po4;
    po4.x = po[0] * inv2[0]; po4.y = po[1] * inv2[1];
    po4.z = po[2] * inv2[2]; po4.w = po[3] * inv2[3];
    ((float4*)outp)[gid] = po4;
  } else {
    // tail: per-row scalar path
    for (int m = 0; m < 4 && row0 + m < B; ++m) {
      const int row = row0 + m;
      float xv = x[row];
      float4 h = h_prev[row];
      float nh2 = fmaf(h.x, h.x, fmaf(h.y, h.y, fmaf(h.z, h.z, h.w * h.w)));
      float nu2 = fmaf(fmaf(qa, xv, qb), xv, qc);
      float inv2 = __builtin_amdgcn_rcpf(nu2 * nh2);
      float hn[4] = {0.f, 0.f, 0.f, 0.f};
      float po = 0.f;
#pragma unroll
      for (int r = 0; r < 16; ++r) {
        float ar = fmaf(AB[r * 4 + 0], h.x,
                   fmaf(AB[r * 4 + 1], h.y,
                   fmaf(AB[r * 4 + 2], h.z, AB[r * 4 + 3] * h.w)));
        float br = fmaf(AB[64 + r * 4 + 0], h.x,
                   fmaf(AB[64 + r * 4 + 1], h.y,
                   fmaf(AB[64 + r * 4 + 2], h.z, AB[64 + r * 4 + 3] * h.w)));
        float tr = fmaf(xv, ar, br);
        float s = tr * tr;
        hn[r & 3] += s;
        po += ((r >> 2) & 1) ? -s : s;
      }
      float4 o;
      o.x = hn[0] * inv2; o.y = hn[1] * inv2;
      o.z = hn[2] * inv2; o.w = hn[3] * inv2;
      h_next[row] = o;
      outp[row] = po * inv2;
    }
  }
}

extern "C" void kernel_launch(void* const* d_in, const int* in_sizes, int n_in,
                              void* d_out, int out_size, void* d_ws, size_t ws_size,
                              hipStream_t stream) {
  const float* x  = (const float*)d_in[0];
  const float* h  = (const float*)d_in[1];
  const float* W  = (const float*)d_in[2];
  const float* bi = (const float*)d_in[3];
  const float* U  = (const float*)d_in[4];
  const float* Ud = (const float*)d_in[5];
  const int B = in_sizes[0];
  float* h_next = (float*)d_out;
  float* out1   = (float*)d_out + 4 * (size_t)B;

  const int nthreads = (B + 3) / 4;
  const int grid = (nthreads + 255) / 256;
  qlstm_fused_kernel<<<grid, 256, 0, stream>>>(
      x, (const float4*)h, W, bi, U, Ud, (float4*)h_next, out1, B);
}

// Round 3
// 87.409 us; speedup vs baseline: 1.0508x; 1.0508x over previous
//
#include <hip/hip_runtime.h>

// QuantumLSTMCell fused single-kernel.
// Per row: u = W*x+b; joint = outer(u,h)/(|u||h|); psi = C*joint; p = psi^2;
// h_next[a] = sum_s p[4s+a]; out = sum_r z_r p_r.
// Folded: psi_r * |u||h| = x*(A_r.h) + (Bm_r.h). A/Bm (16x4 each) built per
// block in LDS from the 16 angles using HW __sinf/__cosf (v_sin/v_cos — the
// libm versions cost ~5us across the grid, the HW ones ~0.5us).
// Each lane processes 4 rows; constants read as ds_read_b128 broadcasts.

__device__ __forceinline__ int ring_perm(int k) {
  // CNOT(0,1), CNOT(1,2), CNOT(2,3), CNOT(3,0) in sequence; wire 0 = MSB.
  int b0 = (k >> 3) & 1, b1 = (k >> 2) & 1, b2 = (k >> 1) & 1, b3 = k & 1;
  b1 ^= b0; b2 ^= b1; b3 ^= b2; b0 ^= b3;
  return (b0 << 3) | (b1 << 2) | (b2 << 1) | b3;
}

__global__ __launch_bounds__(256) void qlstm_fused_kernel(
    const float* __restrict__ x, const float4* __restrict__ h_prev,
    const float* __restrict__ W_in, const float* __restrict__ b_in,
    const float* __restrict__ U, const float* __restrict__ Ud,
    float4* __restrict__ h_next, float* __restrict__ outp, int B) {
  __shared__ float M[16][16];   // running circuit product
  __shared__ float Lm[16][16];  // current layer unitary
  __shared__ float4 AB4[33];    // [0..15] A rows, [16..31] Bm rows, [32]=(qa,qb,qc,_)
  float* AB = (float*)AB4;

  const int t = threadIdx.x;
  {
    const int i = t >> 4, j = t & 15;
    const int pi = ring_perm(i);

    // weights order: U[0], U[1], Udagger[1], Udagger[0]
    float ang[4][4];
#pragma unroll
    for (int q = 0; q < 4; ++q) {
      ang[0][q] = U[q];
      ang[1][q] = U[4 + q];
      ang[2][q] = Ud[4 + q];
      ang[3][q] = Ud[q];
    }

    // layer 0: M = RING @ kron(RY(w0)..RY(w3))  (scatter through perm)
    {
      float kel = 1.f;
#pragma unroll
      for (int q = 0; q < 4; ++q) {
        float c = __cosf(0.5f * ang[0][q]);
        float s = __sinf(0.5f * ang[0][q]);
        int iq = (i >> (3 - q)) & 1, jq = (j >> (3 - q)) & 1;
        kel *= (iq == jq) ? c : (iq ? s : -s);
      }
      M[pi][j] = kel;
    }
    __syncthreads();

#pragma unroll
    for (int l = 1; l < 4; ++l) {
      float kel = 1.f;
#pragma unroll
      for (int q = 0; q < 4; ++q) {
        float c = __cosf(0.5f * ang[l][q]);
        float s = __sinf(0.5f * ang[l][q]);
        int iq = (i >> (3 - q)) & 1, jq = (j >> (3 - q)) & 1;
        kel *= (iq == jq) ? c : (iq ? s : -s);
      }
      Lm[pi][j] = kel;
      __syncthreads();
      float acc = 0.f;
#pragma unroll
      for (int k = 0; k < 16; ++k) acc += Lm[i][k] * M[k][j];
      __syncthreads();  // all reads of M done before overwrite
      M[i][j] = acc;
      __syncthreads();
    }

    // A[r][k] = sum_q W_q * C[r][4q+k]; Bm likewise with b_q
    if (t < 64) {
      const int r = t >> 2, k = t & 3;
      float a = 0.f, bb = 0.f;
#pragma unroll
      for (int q = 0; q < 4; ++q) {
        float c = M[r][4 * q + k];
        a = fmaf(W_in[q], c, a);
        bb = fmaf(b_in[q], c, bb);
      }
      AB[r * 4 + k] = a;
      AB[64 + r * 4 + k] = bb;
    }
    if (t == 0) {
      float qa = 0.f, qb = 0.f, qc = 0.f;
#pragma unroll
      for (int q = 0; q < 4; ++q) {
        qa = fmaf(W_in[q], W_in[q], qa);
        qb = fmaf(2.f * W_in[q], b_in[q], qb);
        qc = fmaf(b_in[q], b_in[q], qc);
      }
      AB[128] = qa; AB[129] = qb; AB[130] = qc;
    }
    __syncthreads();
  }

  // ---- phase 2: 4 rows per lane ----
  const int gid = blockIdx.x * 256 + t;
  const int row0 = gid * 4;
  if (row0 >= B) return;

  const float qa = AB[128], qb = AB[129], qc = AB[130];

  if (row0 + 3 < B) {
    float4 xv4 = ((const float4*)x)[gid];
    float xv[4] = {xv4.x, xv4.y, xv4.z, xv4.w};
    float4 h[4];
#pragma unroll
    for (int m = 0; m < 4; ++m) h[m] = h_prev[row0 + m];

    float inv2[4];
#pragma unroll
    for (int m = 0; m < 4; ++m) {
      float nh2 = fmaf(h[m].x, h[m].x,
                  fmaf(h[m].y, h[m].y,
                  fmaf(h[m].z, h[m].z, h[m].w * h[m].w)));
      float nu2 = fmaf(fmaf(qa, xv[m], qb), xv[m], qc);
      inv2[m] = __builtin_amdgcn_rcpf(nu2 * nh2);
    }

    float hn[4][4] = {};
    float po[4] = {0.f, 0.f, 0.f, 0.f};
#pragma unroll
    for (int r = 0; r < 16; ++r) {
      const float4 a4 = AB4[r];        // ds_read_b128 broadcast
      const float4 b4 = AB4[16 + r];   // ds_read_b128 broadcast
#pragma unroll
      for (int m = 0; m < 4; ++m) {
        float ar = fmaf(a4.x, h[m].x, fmaf(a4.y, h[m].y, fmaf(a4.z, h[m].z, a4.w * h[m].w)));
        float br = fmaf(b4.x, h[m].x, fmaf(b4.y, h[m].y, fmaf(b4.z, h[m].z, b4.w * h[m].w)));
        float tr = fmaf(xv[m], ar, br);
        float s = tr * tr;
        hn[m][r & 3] += s;
        po[m] += ((r >> 2) & 1) ? -s : s;
      }
    }

#pragma unroll
    for (int m = 0; m < 4; ++m) {
      float4 o;
      o.x = hn[m][0] * inv2[m];
      o.y = hn[m][1] * inv2[m];
      o.z = hn[m][2] * inv2[m];
      o.w = hn[m][3] * inv2[m];
      h_next[row0 + m] = o;
    }
    float4 po4;
    po4.x = po[0] * inv2[0]; po4.y = po[1] * inv2[1];
    po4.z = po[2] * inv2[2]; po4.w = po[3] * inv2[3];
    ((float4*)outp)[gid] = po4;
  } else {
    // tail: per-row scalar path (B=2^20 -> not taken, kept for safety)
    for (int m = 0; m < 4 && row0 + m < B; ++m) {
      const int row = row0 + m;
      float xv = x[row];
      float4 h = h_prev[row];
      float nh2 = fmaf(h.x, h.x, fmaf(h.y, h.y, fmaf(h.z, h.z, h.w * h.w)));
      float nu2 = fmaf(fmaf(qa, xv, qb), xv, qc);
      float inv2 = __builtin_amdgcn_rcpf(nu2 * nh2);
      float hn[4] = {0.f, 0.f, 0.f, 0.f};
      float po = 0.f;
#pragma unroll
      for (int r = 0; r < 16; ++r) {
        const float4 a4 = AB4[r];
        const float4 b4 = AB4[16 + r];
        float ar = fmaf(a4.x, h.x, fmaf(a4.y, h.y, fmaf(a4.z, h.z, a4.w * h.w)));
        float br = fmaf(b4.x, h.x, fmaf(b4.y, h.y, fmaf(b4.z, h.z, b4.w * h.w)));
        float tr = fmaf(xv, ar, br);
        float s = tr * tr;
        hn[r & 3] += s;
        po += ((r >> 2) & 1) ? -s : s;
      }
      float4 o;
      o.x = hn[0] * inv2; o.y = hn[1] * inv2;
      o.z = hn[2] * inv2; o.w = hn[3] * inv2;
      h_next[row] = o;
      outp[row] = po * inv2;
    }
  }
}

extern "C" void kernel_launch(void* const* d_in, const int* in_sizes, int n_in,
                              void* d_out, int out_size, void* d_ws, size_t ws_size,
                              hipStream_t stream) {
  const float* x  = (const float*)d_in[0];
  const float* h  = (const float*)d_in[1];
  const float* W  = (const float*)d_in[2];
  const float* bi = (const float*)d_in[3];
  const float* U  = (const float*)d_in[4];
  const float* Ud = (const float*)d_in[5];
  const int B = in_sizes[0];
  float* h_next = (float*)d_out;
  float* out1   = (float*)d_out + 4 * (size_t)B;

  const int nthreads = (B + 3) / 4;
  const int grid = (nthreads + 255) / 256;
  qlstm_fused_kernel<<<grid, 256, 0, stream>>>(
      x, (const float4*)h, W, bi, U, Ud, (float4*)h_next, out1, B);
}